// Round 13
// baseline (49.205 us; speedup 1.0000x reference)
//
#include <hip/hip_runtime.h>
#include <hip/hip_bf16.h>
#include <stdint.h>

typedef __attribute__((ext_vector_type(8))) short bf16x8;
typedef __attribute__((ext_vector_type(4))) float f32x4;

__device__ __forceinline__ unsigned short f2bf(float f) {
  union { float f; uint32_t u; } v; v.f = f;
  uint32_t u = v.u;
  return (unsigned short)((u + 0x7fffu + ((u >> 16) & 1u)) >> 16);
}
__device__ __forceinline__ float bf2f(unsigned short h) {
  union { uint32_t u; float f; } v; v.u = ((uint32_t)h) << 16;
  return v.f;
}

#define GLL(g, l) __builtin_amdgcn_global_load_lds( \
    (const __attribute__((address_space(1))) void*)(g), \
    (__attribute__((address_space(3))) void*)(l), 16, 0, 0)
#define WAITV(N) asm volatile("s_waitcnt vmcnt(" #N ")" ::: "memory")
#define SFENCE() __builtin_amdgcn_sched_barrier(0)
#define RBAR()   __builtin_amdgcn_s_barrier()

// ---------------- fp32 -> bf16 convert (x and Wk|Wq|Wv in one launch) ----------------
__global__ void cvt_all(const float* __restrict__ x,
                        const float* __restrict__ wk, const float* __restrict__ wq,
                        const float* __restrict__ wv,
                        unsigned short* __restrict__ xb, unsigned short* __restrict__ wb) {
  const int i = (blockIdx.x * 256 + threadIdx.x) * 4;
  const float* src; unsigned short* dst; int off;
  if (i < 4194304) { src = x; dst = xb; off = i; }
  else {
    const int j = i - 4194304;
    if (j < 65536)       { src = wk; off = j; }
    else if (j < 131072) { src = wq; off = j - 65536; }
    else                 { src = wv; off = j - 131072; }
    dst = wb + (j - off);
  }
  const float4 v = *(const float4*)(src + off);
  ushort4 o; o.x = f2bf(v.x); o.y = f2bf(v.y); o.z = f2bf(v.z); o.w = f2bf(v.w);
  *(ushort4*)(dst + off) = o;
}

// ---------------- QKV projection GEMM: 128x128 tile, acc 4x4/wave, T4 pipeline ----------------
// grid 384 blocks (64 m x 6 n panels), 256 thr (4 waves, 2m x 2n), 64 KB LDS -> 2 blocks/CU,
// all 384 co-resident. Wave tile 64x64: 8 frag-reads per 16 MFMAs (0.5/MFMA).
__global__ __launch_bounds__(256, 2) void qkv_gemm(
    const unsigned short* __restrict__ xb, const unsigned short* __restrict__ wb,
    const float* __restrict__ pbk, const float* __restrict__ pbq, const float* __restrict__ pbv,
    unsigned short* __restrict__ kb, unsigned short* __restrict__ qtb,
    unsigned short* __restrict__ vb, unsigned short* __restrict__ vtb)
{
  __shared__ unsigned short Alds[2][128 * 64];
  __shared__ unsigned short Blds[2][128 * 64];
  const int tid = threadIdx.x;
  const int lane = tid & 63;
  const int wid = tid >> 6;
  const int wm = wid >> 1, wn = wid & 1;
  const int wg = blockIdx.x;
  const int s = (wg & 7) * 48 + (wg >> 3);   // bijective XCD chunking (384 = 8 x 48)
  const int bx = s & 63, by = s >> 6;        // bx: m-tile 0..63, by: n-panel 0..5
  const int m0 = bx * 128, n0 = by * 128;
  const int l15 = lane & 15, l4 = lane >> 4;

  f32x4 acc[4][4] = {};

  auto stage = [&](int b, int kt) {            // 8 GLL per thread
    const int k0 = kt * 64;
    #pragma unroll
    for (int p = 0; p < 4; ++p) {
      const int e = p * 256 + tid;
      const int row = e >> 3;
      const int cs = (e & 7) ^ (row & 7);
      GLL(xb + (size_t)(m0 + row) * 512 + k0 + cs * 8, &Alds[b][(p * 256 + (tid & ~63)) * 8]);
      GLL(wb + (size_t)(n0 + row) * 512 + k0 + cs * 8, &Blds[b][(p * 256 + (tid & ~63)) * 8]);
    }
  };

  stage(0, 0);
  stage(1, 1);

  for (int kt = 0; kt < 8; ++kt) {
    const int cur = kt & 1;
    if (kt < 7) { WAITV(8); } else { WAITV(0); }   // stage(kt) landed; stage(kt+1) in flight
    RBAR();
    SFENCE();
    #pragma unroll
    for (int kk = 0; kk < 2; ++kk) {
      bf16x8 af[4], bfv[4];
      const int c = kk * 4 + l4;
      #pragma unroll
      for (int i = 0; i < 4; ++i) {
        const int ra = wm * 64 + i * 16 + l15;
        af[i]  = *(const bf16x8*)(&Alds[cur][ra * 64 + ((c ^ (ra & 7)) * 8)]);
        const int rb = wn * 64 + i * 16 + l15;
        bfv[i] = *(const bf16x8*)(&Blds[cur][rb * 64 + ((c ^ (rb & 7)) * 8)]);
      }
      #pragma unroll
      for (int i = 0; i < 4; ++i)
        #pragma unroll
        for (int j = 0; j < 4; ++j)
          acc[i][j] = __builtin_amdgcn_mfma_f32_16x16x32_bf16(af[i], bfv[j], acc[i][j], 0, 0, 0);
    }
    SFENCE();
    RBAR();                                        // all waves done reading buf[cur]
    if (kt < 6) stage(cur, kt + 2);                // refill freed buffer; stays in flight
  }

  #pragma unroll
  for (int i = 0; i < 4; ++i) {
    #pragma unroll
    for (int j = 0; j < 4; ++j) {
      const int rbase = m0 + wm * 64 + i * 16 + l4 * 4;
      const int c = n0 + wn * 64 + j * 16 + l15;
      const float bias = (c < 128) ? pbk[c] : (c < 256) ? pbq[c - 128] : pbv[c - 256];
      unsigned short o[4];
      #pragma unroll
      for (int r = 0; r < 4; ++r) o[r] = f2bf(acc[i][j][r] + bias);
      if (c < 128) {
        #pragma unroll
        for (int r = 0; r < 4; ++r) kb[(size_t)(rbase + r) * 128 + c] = o[r];
      } else if (c < 256) {
        ushort4 t; t.x = o[0]; t.y = o[1]; t.z = o[2]; t.w = o[3];
        *(ushort4*)(qtb + (size_t)(c - 128) * 8192 + rbase) = t;
      } else {
        const int vcol = c - 256;
        #pragma unroll
        for (int r = 0; r < 4; ++r) vb[(size_t)(rbase + r) * 512 + vcol] = o[r];
        ushort4 t; t.x = o[0]; t.y = o[1]; t.z = o[2]; t.w = o[3];
        *(ushort4*)(vtb + (size_t)vcol * 8192 + rbase) = t;
      }
    }
  }
}

// ---------------- [G|H] = Q^T [Q|V]  (LDS-staged split-K, T4 pipeline; R12) ----------------
__global__ __launch_bounds__(512) void gh_gemm(
    const unsigned short* __restrict__ qtb, const unsigned short* __restrict__ vtb,
    unsigned short* __restrict__ pb)
{
  __shared__ unsigned short Alds[2][128 * 64];
  __shared__ unsigned short Blds[2][80 * 64];
  const int tid = threadIdx.x, lane = tid & 63, wid = tid >> 6;
  const int l15 = lane & 15, l4 = lane >> 4;
  const int kc = blockIdx.x, nq = blockIdx.y;
  const int g0 = kc * 256;
  const int m0 = wid * 16;

  f32x4 acc[5] = {};

  auto stage = [&](int b, int st) {
    const int gs = g0 + st * 64;
    #pragma unroll
    for (int p = 0; p < 2; ++p) {
      const int e = p * 512 + tid;
      const int row = e >> 3;
      const int cs = (e & 7) ^ (row & 7);
      GLL(qtb + (size_t)row * 8192 + gs + cs * 8, &Alds[b][(p * 512 + (tid & ~63)) * 8]);
    }
    {
      const int row = tid >> 3;
      const int cglob = nq * 80 + row;
      const unsigned short* src = (cglob < 128) ? (qtb + (size_t)cglob * 8192)
                                                : (vtb + (size_t)(cglob - 128) * 8192);
      const int cs = (tid & 7) ^ (row & 7);
      GLL(src + gs + cs * 8, &Blds[b][(tid & ~63) * 8]);
    }
    if (tid < 128) {
      const int e = 512 + tid;
      const int row = e >> 3;
      const int cglob = nq * 80 + row;
      const unsigned short* src = (cglob < 128) ? (qtb + (size_t)cglob * 8192)
                                                : (vtb + (size_t)(cglob - 128) * 8192);
      const int cs = (e & 7) ^ (row & 7);
      GLL(src + gs + cs * 8, &Blds[b][(512 + (tid & ~63)) * 8]);
    }
  };

  stage(0, 0);
  stage(1, 1);

  for (int st = 0; st < 4; ++st) {
    const int cur = st & 1;
    if (st < 3) { WAITV(3); } else { WAITV(0); }
    RBAR();
    SFENCE();
    #pragma unroll
    for (int ks = 0; ks < 2; ++ks) {
      const int ra = m0 + l15;
      const int ca = ks * 4 + l4;
      const bf16x8 af = *(const bf16x8*)(&Alds[cur][ra * 64 + ((ca ^ (ra & 7)) * 8)]);
      #pragma unroll
      for (int nf = 0; nf < 5; ++nf) {
        const int rb = nf * 16 + l15;
        const bf16x8 bf = *(const bf16x8*)(&Blds[cur][rb * 64 + ((ca ^ (rb & 7)) * 8)]);
        acc[nf] = __builtin_amdgcn_mfma_f32_16x16x32_bf16(af, bf, acc[nf], 0, 0, 0);
      }
    }
    SFENCE();
    RBAR();
    if (st < 2) stage(cur, st + 2);
  }

  #pragma unroll
  for (int nf = 0; nf < 5; ++nf) {
    const int col = nq * 80 + nf * 16 + l15;
    #pragma unroll
    for (int r = 0; r < 4; ++r) {
      const int row = m0 + l4 * 4 + r;
      pb[((size_t)kc * 128 + row) * 640 + col] = f2bf(acc[nf][r]);
    }
  }
}

// Sum 32 bf16 partials -> Gb [128][128] bf16, Hbt [512][128] bf16 (H transposed).
__global__ void gh_finalize(const unsigned short* __restrict__ pb,
                            unsigned short* __restrict__ Gb, unsigned short* __restrict__ Hbt) {
  const int idx = blockIdx.x * 256 + threadIdx.x;  // 0..81919
  float s = 0.f;
  #pragma unroll
  for (int p = 0; p < 32; ++p) s += bf2f(pb[(size_t)p * 81920 + idx]);
  const int m = idx / 640, c = idx % 640;
  if (c < 128) Gb[m * 128 + c] = f2bf(s);
  else         Hbt[(size_t)(c - 128) * 128 + m] = f2bf(s);
}

// ---------------- fused uvn_out: rnorm (k_i G k_i^T) + out = (K·H)*rnm + v ----------------
// grid (64 m-tiles x 4 n-tiles), 512 thr. Kld+Gld+Hld staged (96 KB); rnorm computed
// per-block (4x redundant across n-tiles) while H loads stay in flight (vmcnt(4)).
__global__ __launch_bounds__(512, 2) void uvn_out(
    const unsigned short* __restrict__ kb, const unsigned short* __restrict__ Gb,
    const unsigned short* __restrict__ Hbt, const unsigned short* __restrict__ vb,
    float* __restrict__ out)
{
  __shared__ unsigned short Kld[128 * 128];  // [row][k] swizzled, 32 KB
  __shared__ unsigned short Gld[128 * 128];  // [grow][k] swizzled, 32 KB
  __shared__ unsigned short Hld[128 * 128];  // [col][k] swizzled, 32 KB
  __shared__ float rnm_lds[128];
  const int tid = threadIdx.x, lane = tid & 63, wid = tid >> 6;
  const int l15 = lane & 15, l4 = lane >> 4;
  const int m0 = blockIdx.x * 128, n0 = blockIdx.y * 128;
  const int wm = wid >> 2, wn = wid & 3;

  // stage K, G first (needed by rnorm phase), then H (drains later under vmcnt(4))
  #pragma unroll
  for (int p = 0; p < 4; ++p) {
    const int e = p * 512 + tid;
    const int row = e >> 4, ch = e & 15;
    const int cs = ch ^ ((row & 7) << 1);
    GLL(kb + (size_t)(m0 + row) * 128 + cs * 8, &Kld[(e & ~63) * 8]);
  }
  #pragma unroll
  for (int p = 0; p < 4; ++p) {
    const int e = p * 512 + tid;
    const int row = e >> 4, ch = e & 15;
    const int cs = ch ^ ((row & 7) << 1);
    GLL(Gb + (size_t)row * 128 + cs * 8, &Gld[(e & ~63) * 8]);
  }
  #pragma unroll
  for (int p = 0; p < 4; ++p) {
    const int e = p * 512 + tid;
    const int row = e >> 4, ch = e & 15;
    const int cs = ch ^ ((row & 7) << 1);
    GLL(Hbt + (size_t)(n0 + row) * 128 + cs * 8, &Hld[(e & ~63) * 8]);
  }
  WAITV(4);            // K+G landed; H's 4 loads still in flight
  __syncthreads();

  // ---- rnorm phase: wave wid owns rows wid*16..+16, full 128-col rowdot ----
  {
    bf16x8 afn[4];
    #pragma unroll
    for (int ks = 0; ks < 4; ++ks) {
      const int row = wid * 16 + l15, ci = ks * 4 + l4;
      afn[ks] = *(const bf16x8*)((const char*)Kld + row * 256 + ((ci ^ ((row & 7) << 1)) * 16));
    }
    f32x4 tac[8] = {};
    #pragma unroll
    for (int ks = 0; ks < 4; ++ks) {
      const int ci = ks * 4 + l4;
      #pragma unroll
      for (int nf = 0; nf < 8; ++nf) {
        const int grow = nf * 16 + l15;       // G symmetric: B^T rows = G rows
        const bf16x8 bf = *(const bf16x8*)((const char*)Gld + grow * 256 +
                                           ((ci ^ ((grow & 7) << 1)) * 16));
        tac[nf] = __builtin_amdgcn_mfma_f32_16x16x32_bf16(afn[ks], bf, tac[nf], 0, 0, 0);
      }
    }
    float ssq[4] = {0.f, 0.f, 0.f, 0.f};
    #pragma unroll
    for (int nf = 0; nf < 8; ++nf) {
      #pragma unroll
      for (int r = 0; r < 4; ++r) {
        const int row = wid * 16 + l4 * 4 + r;
        const int col = nf * 16 + l15;
        const unsigned short kv = *(const unsigned short*)((const char*)Kld + row * 256 +
            (((col >> 3) ^ ((row & 7) << 1)) * 16) + (col & 7) * 2);
        ssq[r] += tac[nf][r] * bf2f(kv);
      }
    }
    #pragma unroll
    for (int d = 1; d < 16; d <<= 1)
      #pragma unroll
      for (int r = 0; r < 4; ++r) ssq[r] += __shfl_xor(ssq[r], d);
    if (l15 == 0) {
      #pragma unroll
      for (int r = 0; r < 4; ++r)
        rnm_lds[wid * 16 + l4 * 4 + r] = 1.0f / fmaxf(sqrtf(ssq[r]), 1e-12f);
    }
  }

  WAITV(0);            // H staged
  __syncthreads();     // rnm_lds + Hld visible

  // ---- U phase: wave (wm,wn): rows wm*64..+64, cols wn*32..+32 ----
  f32x4 acc[4][2] = {};
  #pragma unroll
  for (int ks = 0; ks < 4; ++ks) {
    const int ci = ks * 4 + l4;
    bf16x8 af[4], bf[2];
    #pragma unroll
    for (int i = 0; i < 4; ++i) {
      const int row = wm * 64 + i * 16 + l15;
      af[i] = *(const bf16x8*)((const char*)Kld + row * 256 + ((ci ^ ((row & 7) << 1)) * 16));
    }
    #pragma unroll
    for (int j = 0; j < 2; ++j) {
      const int col = wn * 32 + j * 16 + l15;
      bf[j] = *(const bf16x8*)((const char*)Hld + col * 256 + ((ci ^ ((col & 7) << 1)) * 16));
    }
    #pragma unroll
    for (int i = 0; i < 4; ++i)
      #pragma unroll
      for (int j = 0; j < 2; ++j)
        acc[i][j] = __builtin_amdgcn_mfma_f32_16x16x32_bf16(af[i], bf[j], acc[i][j], 0, 0, 0);
  }

  #pragma unroll
  for (int i = 0; i < 4; ++i) {
    float rn[4];
    #pragma unroll
    for (int r = 0; r < 4; ++r) rn[r] = rnm_lds[wm * 64 + i * 16 + l4 * 4 + r];
    #pragma unroll
    for (int j = 0; j < 2; ++j) {
      const int col = n0 + wn * 32 + j * 16 + l15;
      #pragma unroll
      for (int r = 0; r < 4; ++r) {
        const int row = m0 + wm * 64 + i * 16 + l4 * 4 + r;
        out[(size_t)row * 512 + col] =
            acc[i][j][r] * rn[r] + bf2f(vb[(size_t)row * 512 + col]);
      }
    }
  }
}

extern "C" void kernel_launch(void* const* d_in, const int* in_sizes, int n_in,
                              void* d_out, int out_size, void* d_ws, size_t ws_size,
                              hipStream_t stream) {
  const float* x  = (const float*)d_in[0];
  const float* Wk = (const float*)d_in[1];
  const float* bk = (const float*)d_in[2];
  const float* Wq = (const float*)d_in[3];
  const float* bq = (const float*)d_in[4];
  const float* Wv = (const float*)d_in[5];
  const float* bv = (const float*)d_in[6];
  float* out = (float*)d_out;

  char* ws = (char*)d_ws;
  unsigned short* xb   = (unsigned short*)(ws);              //  8192*512*2 = 8,388,608
  unsigned short* wb   = (unsigned short*)(ws + 8388608);    //   768*512*2 =   786,432
  unsigned short* kb   = (unsigned short*)(ws + 9175040);    //  8192*128*2 = 2,097,152
  unsigned short* vb   = (unsigned short*)(ws + 11272192);   //  8192*512*2 = 8,388,608
  unsigned short* vtb  = (unsigned short*)(ws + 19660800);   //   512*8192*2= 8,388,608
  unsigned short* qtb  = (unsigned short*)(ws + 28049408);   //   128*8192*2= 2,097,152
  unsigned short* pb   = (unsigned short*)(ws + 30146560);   //  32*128*640*2=5,242,880
  unsigned short* Gb   = (unsigned short*)(ws + 35389440);   //   128*128*2 =    32,768
  unsigned short* Hbt  = (unsigned short*)(ws + 35422208);   //   512*128*2 =   131,072

  cvt_all<<<4480, 256, 0, stream>>>(x, Wk, Wq, Wv, xb, wb);
  qkv_gemm<<<384, 256, 0, stream>>>(xb, wb, bk, bq, bv, kb, qtb, vb, vtb);
  gh_gemm<<<dim3(32, 8), 512, 0, stream>>>(qtb, vtb, pb);
  gh_finalize<<<320, 256, 0, stream>>>(pb, Gb, Hbt);
  uvn_out<<<dim3(64, 4), 512, 0, stream>>>(kb, Gb, Hbt, vb, out);
}

// Round 14
// 45.670 us; speedup vs baseline: 1.0774x; 1.0774x over previous
//
#include <hip/hip_runtime.h>
#include <hip/hip_bf16.h>
#include <stdint.h>

typedef __attribute__((ext_vector_type(8))) short bf16x8;
typedef __attribute__((ext_vector_type(4))) float f32x4;

__device__ __forceinline__ unsigned short f2bf(float f) {
  union { float f; uint32_t u; } v; v.f = f;
  uint32_t u = v.u;
  return (unsigned short)((u + 0x7fffu + ((u >> 16) & 1u)) >> 16);
}
__device__ __forceinline__ float bf2f(unsigned short h) {
  union { uint32_t u; float f; } v; v.u = ((uint32_t)h) << 16;
  return v.f;
}

#define GLL(g, l) __builtin_amdgcn_global_load_lds( \
    (const __attribute__((address_space(1))) void*)(g), \
    (__attribute__((address_space(3))) void*)(l), 16, 0, 0)
#define WAITV(N) asm volatile("s_waitcnt vmcnt(" #N ")" ::: "memory")
#define SFENCE() __builtin_amdgcn_sched_barrier(0)
#define RBAR()   __builtin_amdgcn_s_barrier()

// ---------------- fp32 -> bf16 convert (x and Wk|Wq|Wv in one launch) ----------------
__global__ void cvt_all(const float* __restrict__ x,
                        const float* __restrict__ wk, const float* __restrict__ wq,
                        const float* __restrict__ wv,
                        unsigned short* __restrict__ xb, unsigned short* __restrict__ wb) {
  const int i = (blockIdx.x * 256 + threadIdx.x) * 4;
  const float* src; unsigned short* dst; int off;
  if (i < 4194304) { src = x; dst = xb; off = i; }
  else {
    const int j = i - 4194304;
    if (j < 65536)       { src = wk; off = j; }
    else if (j < 131072) { src = wq; off = j - 65536; }
    else                 { src = wv; off = j - 131072; }
    dst = wb + (j - off);
  }
  const float4 v = *(const float4*)(src + off);
  ushort4 o; o.x = f2bf(v.x); o.y = f2bf(v.y); o.z = f2bf(v.z); o.w = f2bf(v.w);
  *(ushort4*)(dst + off) = o;
}

// ---------------- QKV projection GEMM: 64x128 tile, 768 blocks (3/CU), T4 pipeline ----------------
// XCD m-locality mapping: each XCD owns 16 m-tiles x all 6 panels; per-XCD x footprint 1 MB
// (L2-resident) + W 0.79 MB (L2-resident) -> xb HBM traffic = compulsory 8.4 MB.
__global__ __launch_bounds__(256, 3) void qkv_gemm(
    const unsigned short* __restrict__ xb, const unsigned short* __restrict__ wb,
    const float* __restrict__ pbk, const float* __restrict__ pbq, const float* __restrict__ pbv,
    unsigned short* __restrict__ kb, unsigned short* __restrict__ qtb,
    unsigned short* __restrict__ vb, unsigned short* __restrict__ vtb)
{
  __shared__ unsigned short Alds[2][64 * 64];
  __shared__ unsigned short Blds[2][128 * 64];
  const int tid = threadIdx.x;
  const int lane = tid & 63;
  const int wid = tid >> 6;
  const int wm = wid >> 1, wn = wid & 1;
  const int wg = blockIdx.x;
  const int xcd = wg & 7, sl = wg >> 3;      // sl: 0..95 within XCD
  const int bx = xcd * 16 + sl / 6;          // 16 m-tiles per XCD (m-tile = 64 rows... x2)
  const int by = sl % 6;                     // 6 consecutive blocks share one x-tile
  const int m0 = bx * 64, n0 = by * 128;
  const int l15 = lane & 15, l4 = lane >> 4;

  f32x4 acc[2][4] = {};

  auto stage = [&](int b, int kt) {            // 6 GLL per thread (uniform)
    const int k0 = kt * 64;
    #pragma unroll
    for (int p = 0; p < 2; ++p) {
      const int e = p * 256 + tid;
      const int row = e >> 3;
      const int cs = (e & 7) ^ (row & 7);
      GLL(xb + (size_t)(m0 + row) * 512 + k0 + cs * 8, &Alds[b][(p * 256 + (tid & ~63)) * 8]);
    }
    #pragma unroll
    for (int p = 0; p < 4; ++p) {
      const int e = p * 256 + tid;
      const int row = e >> 3;
      const int cs = (e & 7) ^ (row & 7);
      GLL(wb + (size_t)(n0 + row) * 512 + k0 + cs * 8, &Blds[b][(p * 256 + (tid & ~63)) * 8]);
    }
  };

  stage(0, 0);
  stage(1, 1);

  for (int kt = 0; kt < 8; ++kt) {
    const int cur = kt & 1;
    if (kt < 7) { WAITV(6); } else { WAITV(0); }   // stage(kt) landed; stage(kt+1) in flight
    RBAR();
    SFENCE();
    #pragma unroll
    for (int kk = 0; kk < 2; ++kk) {
      bf16x8 af[2], bfv[4];
      #pragma unroll
      for (int i = 0; i < 2; ++i) {
        const int ra = wm * 32 + i * 16 + l15;
        const int c  = kk * 4 + l4;
        af[i] = *(const bf16x8*)(&Alds[cur][ra * 64 + ((c ^ (ra & 7)) * 8)]);
      }
      #pragma unroll
      for (int j = 0; j < 4; ++j) {
        const int rb = wn * 64 + j * 16 + l15;
        const int c  = kk * 4 + l4;
        bfv[j] = *(const bf16x8*)(&Blds[cur][rb * 64 + ((c ^ (rb & 7)) * 8)]);
      }
      #pragma unroll
      for (int i = 0; i < 2; ++i)
        #pragma unroll
        for (int j = 0; j < 4; ++j)
          acc[i][j] = __builtin_amdgcn_mfma_f32_16x16x32_bf16(af[i], bfv[j], acc[i][j], 0, 0, 0);
    }
    SFENCE();
    RBAR();                                        // all waves done reading buf[cur]
    if (kt < 6) stage(cur, kt + 2);                // refill freed buffer; stays in flight
  }

  #pragma unroll
  for (int i = 0; i < 2; ++i) {
    #pragma unroll
    for (int j = 0; j < 4; ++j) {
      const int rbase = m0 + wm * 32 + i * 16 + l4 * 4;
      const int c = n0 + wn * 64 + j * 16 + l15;
      const float bias = (c < 128) ? pbk[c] : (c < 256) ? pbq[c - 128] : pbv[c - 256];
      unsigned short o[4];
      #pragma unroll
      for (int r = 0; r < 4; ++r) o[r] = f2bf(acc[i][j][r] + bias);
      if (c < 128) {
        #pragma unroll
        for (int r = 0; r < 4; ++r) kb[(size_t)(rbase + r) * 128 + c] = o[r];
      } else if (c < 256) {
        ushort4 t; t.x = o[0]; t.y = o[1]; t.z = o[2]; t.w = o[3];
        *(ushort4*)(qtb + (size_t)(c - 128) * 8192 + rbase) = t;
      } else {
        const int vcol = c - 256;
        #pragma unroll
        for (int r = 0; r < 4; ++r) vb[(size_t)(rbase + r) * 512 + vcol] = o[r];
        ushort4 t; t.x = o[0]; t.y = o[1]; t.z = o[2]; t.w = o[3];
        *(ushort4*)(vtb + (size_t)vcol * 8192 + rbase) = t;
      }
    }
  }
}

// ---------------- [G|H] = Q^T [Q|V]  (LDS-staged split-K, T4 pipeline) ----------------
__global__ __launch_bounds__(512) void gh_gemm(
    const unsigned short* __restrict__ qtb, const unsigned short* __restrict__ vtb,
    unsigned short* __restrict__ pb)
{
  __shared__ unsigned short Alds[2][128 * 64];
  __shared__ unsigned short Blds[2][80 * 64];
  const int tid = threadIdx.x, lane = tid & 63, wid = tid >> 6;
  const int l15 = lane & 15, l4 = lane >> 4;
  const int kc = blockIdx.x, nq = blockIdx.y;
  const int g0 = kc * 256;
  const int m0 = wid * 16;

  f32x4 acc[5] = {};

  auto stage = [&](int b, int st) {             // 3 GLL/thread (+1 for tid<128)
    const int gs = g0 + st * 64;
    #pragma unroll
    for (int p = 0; p < 2; ++p) {
      const int e = p * 512 + tid;
      const int row = e >> 3;
      const int cs = (e & 7) ^ (row & 7);
      GLL(qtb + (size_t)row * 8192 + gs + cs * 8, &Alds[b][(p * 512 + (tid & ~63)) * 8]);
    }
    {
      const int row = tid >> 3;
      const int cglob = nq * 80 + row;
      const unsigned short* src = (cglob < 128) ? (qtb + (size_t)cglob * 8192)
                                                : (vtb + (size_t)(cglob - 128) * 8192);
      const int cs = (tid & 7) ^ (row & 7);
      GLL(src + gs + cs * 8, &Blds[b][(tid & ~63) * 8]);
    }
    if (tid < 128) {
      const int e = 512 + tid;
      const int row = e >> 3;
      const int cglob = nq * 80 + row;
      const unsigned short* src = (cglob < 128) ? (qtb + (size_t)cglob * 8192)
                                                : (vtb + (size_t)(cglob - 128) * 8192);
      const int cs = (e & 7) ^ (row & 7);
      GLL(src + gs + cs * 8, &Blds[b][(512 + (tid & ~63)) * 8]);
    }
  };

  stage(0, 0);
  stage(1, 1);

  for (int st = 0; st < 4; ++st) {
    const int cur = st & 1;
    if (st < 3) { WAITV(3); } else { WAITV(0); }  // 4-load threads over-wait by 1: safe
    RBAR();
    SFENCE();
    #pragma unroll
    for (int ks = 0; ks < 2; ++ks) {
      const int ra = m0 + l15;
      const int ca = ks * 4 + l4;
      const bf16x8 af = *(const bf16x8*)(&Alds[cur][ra * 64 + ((ca ^ (ra & 7)) * 8)]);
      #pragma unroll
      for (int nf = 0; nf < 5; ++nf) {
        const int rb = nf * 16 + l15;
        const bf16x8 bf = *(const bf16x8*)(&Blds[cur][rb * 64 + ((ca ^ (rb & 7)) * 8)]);
        acc[nf] = __builtin_amdgcn_mfma_f32_16x16x32_bf16(af, bf, acc[nf], 0, 0, 0);
      }
    }
    SFENCE();
    RBAR();
    if (st < 2) stage(cur, st + 2);
  }

  #pragma unroll
  for (int nf = 0; nf < 5; ++nf) {
    const int col = nq * 80 + nf * 16 + l15;
    #pragma unroll
    for (int r = 0; r < 4; ++r) {
      const int row = m0 + l4 * 4 + r;
      pb[((size_t)kc * 128 + row) * 640 + col] = f2bf(acc[nf][r]);
    }
  }
}

// Sum 32 bf16 partials -> Gb [128][128] bf16, Hbt [512][128] bf16 (H transposed).
__global__ void gh_finalize(const unsigned short* __restrict__ pb,
                            unsigned short* __restrict__ Gb, unsigned short* __restrict__ Hbt) {
  const int idx = blockIdx.x * 256 + threadIdx.x;  // 0..81919
  float s = 0.f;
  #pragma unroll
  for (int p = 0; p < 32; ++p) s += bf2f(pb[(size_t)p * 81920 + idx]);
  const int m = idx / 640, c = idx % 640;
  if (c < 128) Gb[m * 128 + c] = f2bf(s);
  else         Hbt[(size_t)(c - 128) * 128 + m] = f2bf(s);
}

// ---------------- tnorm: rnm_i = 1/max(sqrt(k_i G k_i^T), eps) ----------------
__global__ __launch_bounds__(512, 2) void tnorm(
    const unsigned short* __restrict__ kb, const unsigned short* __restrict__ Gb,
    float* __restrict__ rnm)
{
  __shared__ unsigned short Kld[128 * 128];  // 32 KB, 16B-chunk XOR swizzle
  __shared__ unsigned short Gld[128 * 128];  // 32 KB
  const int tid = threadIdx.x, lane = tid & 63, wid = tid >> 6;
  const int l15 = lane & 15, l4 = lane >> 4;
  const int m0 = blockIdx.x * 128;

  #pragma unroll
  for (int p = 0; p < 4; ++p) {
    const int e = p * 512 + tid;
    const int row = e >> 4, ch = e & 15;
    const int cs = ch ^ ((row & 7) << 1);
    GLL(kb + (size_t)(m0 + row) * 128 + cs * 8, &Kld[(e & ~63) * 8]);
    GLL(Gb + (size_t)row * 128 + cs * 8,        &Gld[(e & ~63) * 8]);
  }
  WAITV(0);
  __syncthreads();

  bf16x8 af[4];
  #pragma unroll
  for (int ks = 0; ks < 4; ++ks) {
    const int row = wid * 16 + l15, ci = ks * 4 + l4;
    af[ks] = *(const bf16x8*)((const char*)Kld + row * 256 + ((ci ^ ((row & 7) << 1)) * 16));
  }
  f32x4 tac[8] = {};
  #pragma unroll
  for (int ks = 0; ks < 4; ++ks) {
    #pragma unroll
    for (int nf = 0; nf < 8; ++nf) {
      const int grow = nf * 16 + l15, ci = ks * 4 + l4;   // G symmetric
      const bf16x8 bf = *(const bf16x8*)((const char*)Gld + grow * 256 +
                                         ((ci ^ ((grow & 7) << 1)) * 16));
      tac[nf] = __builtin_amdgcn_mfma_f32_16x16x32_bf16(af[ks], bf, tac[nf], 0, 0, 0);
    }
  }

  float ssq[4] = {0.f, 0.f, 0.f, 0.f};
  #pragma unroll
  for (int nf = 0; nf < 8; ++nf) {
    #pragma unroll
    for (int r = 0; r < 4; ++r) {
      const int row = wid * 16 + l4 * 4 + r;
      const int col = nf * 16 + l15;
      const unsigned short kv = *(const unsigned short*)((const char*)Kld + row * 256 +
          ((((col >> 3)) ^ ((row & 7) << 1)) * 16) + (col & 7) * 2);
      ssq[r] += tac[nf][r] * bf2f(kv);
    }
  }
  #pragma unroll
  for (int d = 1; d < 16; d <<= 1)
    #pragma unroll
    for (int r = 0; r < 4; ++r) ssq[r] += __shfl_xor(ssq[r], d);
  if (l15 == 0) {
    #pragma unroll
    for (int r = 0; r < 4; ++r)
      rnm[m0 + wid * 16 + l4 * 4 + r] = 1.0f / fmaxf(sqrtf(ssq[r]), 1e-12f);
  }
}

// ---------------- uv_out: out = (K·H)*rnm + v ----------------
__global__ __launch_bounds__(512, 4) void uv_out(
    const unsigned short* __restrict__ kb, const unsigned short* __restrict__ Hbt,
    const float* __restrict__ rnm, const unsigned short* __restrict__ vb,
    float* __restrict__ out)
{
  __shared__ unsigned short Kld[128 * 128];  // [row][k] swizzled
  __shared__ unsigned short Hld[128 * 128];  // [col][k] swizzled
  const int tid = threadIdx.x, lane = tid & 63, wid = tid >> 6;
  const int l15 = lane & 15, l4 = lane >> 4;
  const int m0 = blockIdx.x * 128, n0 = blockIdx.y * 128;
  const int wm = wid >> 2, wn = wid & 3;

  #pragma unroll
  for (int p = 0; p < 4; ++p) {
    const int e = p * 512 + tid;
    const int row = e >> 4, ch = e & 15;
    const int cs = ch ^ ((row & 7) << 1);
    GLL(kb  + (size_t)(m0 + row) * 128 + cs * 8, &Kld[(e & ~63) * 8]);
    GLL(Hbt + (size_t)(n0 + row) * 128 + cs * 8, &Hld[(e & ~63) * 8]);
  }
  WAITV(0);
  __syncthreads();

  f32x4 acc[4][2] = {};
  #pragma unroll
  for (int ks = 0; ks < 4; ++ks) {
    const int ci = ks * 4 + l4;
    bf16x8 af[4], bf[2];
    #pragma unroll
    for (int i = 0; i < 4; ++i) {
      const int row = wm * 64 + i * 16 + l15;
      af[i] = *(const bf16x8*)((const char*)Kld + row * 256 + ((ci ^ ((row & 7) << 1)) * 16));
    }
    #pragma unroll
    for (int j = 0; j < 2; ++j) {
      const int col = wn * 32 + j * 16 + l15;
      bf[j] = *(const bf16x8*)((const char*)Hld + col * 256 + ((ci ^ ((col & 7) << 1)) * 16));
    }
    #pragma unroll
    for (int i = 0; i < 4; ++i)
      #pragma unroll
      for (int j = 0; j < 2; ++j)
        acc[i][j] = __builtin_amdgcn_mfma_f32_16x16x32_bf16(af[i], bf[j], acc[i][j], 0, 0, 0);
  }

  #pragma unroll
  for (int i = 0; i < 4; ++i) {
    float rn[4];
    #pragma unroll
    for (int r = 0; r < 4; ++r) rn[r] = rnm[m0 + wm * 64 + i * 16 + l4 * 4 + r];
    #pragma unroll
    for (int j = 0; j < 2; ++j) {
      const int col = n0 + wn * 32 + j * 16 + l15;
      #pragma unroll
      for (int r = 0; r < 4; ++r) {
        const int row = m0 + wm * 64 + i * 16 + l4 * 4 + r;
        out[(size_t)row * 512 + col] =
            acc[i][j][r] * rn[r] + bf2f(vb[(size_t)row * 512 + col]);
      }
    }
  }
}

extern "C" void kernel_launch(void* const* d_in, const int* in_sizes, int n_in,
                              void* d_out, int out_size, void* d_ws, size_t ws_size,
                              hipStream_t stream) {
  const float* x  = (const float*)d_in[0];
  const float* Wk = (const float*)d_in[1];
  const float* bk = (const float*)d_in[2];
  const float* Wq = (const float*)d_in[3];
  const float* bq = (const float*)d_in[4];
  const float* Wv = (const float*)d_in[5];
  const float* bv = (const float*)d_in[6];
  float* out = (float*)d_out;

  char* ws = (char*)d_ws;
  unsigned short* xb   = (unsigned short*)(ws);              //  8192*512*2 = 8,388,608
  unsigned short* wb   = (unsigned short*)(ws + 8388608);    //   768*512*2 =   786,432
  unsigned short* kb   = (unsigned short*)(ws + 9175040);    //  8192*128*2 = 2,097,152
  unsigned short* vb   = (unsigned short*)(ws + 11272192);   //  8192*512*2 = 8,388,608
  unsigned short* vtb  = (unsigned short*)(ws + 19660800);   //   512*8192*2= 8,388,608
  unsigned short* qtb  = (unsigned short*)(ws + 28049408);   //   128*8192*2= 2,097,152
  unsigned short* pb   = (unsigned short*)(ws + 30146560);   //  32*128*640*2=5,242,880
  unsigned short* Gb   = (unsigned short*)(ws + 35389440);   //   128*128*2 =    32,768
  unsigned short* Hbt  = (unsigned short*)(ws + 35422208);   //   512*128*2 =   131,072
  float*          rnm  = (float*)(ws + 35553280);            //   8192*4    =    32,768

  cvt_all<<<4480, 256, 0, stream>>>(x, Wk, Wq, Wv, xb, wb);
  qkv_gemm<<<768, 256, 0, stream>>>(xb, wb, bk, bq, bv, kb, qtb, vb, vtb);
  gh_gemm<<<dim3(32, 8), 512, 0, stream>>>(qtb, vtb, pb);
  gh_finalize<<<320, 256, 0, stream>>>(pb, Gb, Hbt);
  tnorm<<<64, 512, 0, stream>>>(kb, Gb, rnm);
  uv_out<<<dim3(64, 4), 512, 0, stream>>>(kb, Hbt, rnm, vb, out);
}